// Round 8
// baseline (154.435 us; speedup 1.0000x reference)
//
#include <hip/hip_runtime.h>
#include <hip/hip_bf16.h>

typedef __attribute__((ext_vector_type(8))) short bf16x8;
typedef __attribute__((ext_vector_type(4))) float f32x4;
typedef __attribute__((ext_vector_type(16))) float f32x16;
typedef __attribute__((ext_vector_type(2))) float f32x2;
typedef unsigned short u16;

#define Bc   2
#define Sc   2048
#define Dc   1024
#define Hc   16
#define HDc  64
#define ROTc 32
#define Mrows 4096  // B*S

__device__ __forceinline__ u16 f2bf(float x) {
  union { float f; unsigned u; } v{x};
  unsigned r = v.u + 0x7fffu + ((v.u >> 16) & 1u);
  return (u16)(r >> 16);
}
__device__ __forceinline__ float bf2f(u16 x) {
  union { unsigned u; float f; } v{(unsigned)x << 16};
  return v.f;
}
__device__ __forceinline__ unsigned cvtpk(float a, float b) {
  unsigned r;
  asm("v_cvt_pk_bf16_f32 %0, %1, %2" : "=v"(r) : "v"(a), "v"(b));
  return r;
}
__device__ __forceinline__ f32x2 pmax2(f32x2 a, f32x2 b) {
  f32x2 r;
  r.x = fmaxf(a.x, b.x);
  r.y = fmaxf(a.y, b.y);
  return r;
}

__device__ __forceinline__ void gload_lds16(const void* g, void* l) {
  __builtin_amdgcn_global_load_lds(
      (const __attribute__((address_space(1))) void*)g,
      (__attribute__((address_space(3))) void*)l, 16, 0, 0);
}

// ---------------- f32 -> bf16 conversion (hidden + 4 weights in one grid) --
__global__ void cvt_all(const float* __restrict__ h, const float* __restrict__ q,
                        const float* __restrict__ k, const float* __restrict__ v,
                        const float* __restrict__ o,
                        u16* __restrict__ hb, u16* __restrict__ qb, u16* __restrict__ kb,
                        u16* __restrict__ vb, u16* __restrict__ ob) {
  size_t i = ((size_t)blockIdx.x * 256 + threadIdx.x) * 4;
  const float* s;
  u16* d;
  size_t off;
  if (i < (size_t)Mrows * Dc) {
    s = h; d = hb; off = i;
  } else {
    size_t j = i - (size_t)Mrows * Dc;
    int w = (int)(j >> 20);            // 1M elements per weight
    off = j & ((1u << 20) - 1);
    s = (w == 0) ? q : (w == 1) ? k : (w == 2) ? v : o;
    d = (w == 0) ? qb : (w == 1) ? kb : (w == 2) ? vb : ob;
  }
  float4 val = *reinterpret_cast<const float4*>(s + off);
  u16 r0 = f2bf(val.x), r1 = f2bf(val.y), r2 = f2bf(val.z), r3 = f2bf(val.w);
  ushort4 outv = {r0, r1, r2, r3};
  *reinterpret_cast<ushort4*>(d + off) = outv;
}

// ---------------- fused QKV NT GEMM, 128x128 tile, grid (32, 24) ----------
// blockIdx.y: [0,8)=Q, [8,16)=K, [16,24)=V(store transposed).
__global__ void gemm_qkv(const u16* __restrict__ A, const u16* __restrict__ W0,
                         const u16* __restrict__ W1, const u16* __restrict__ W2,
                         u16* __restrict__ Qo, u16* __restrict__ Ko,
                         u16* __restrict__ Vo) {
  __shared__ u16 As[128 * 32];
  __shared__ u16 Bs[128 * 32];
  const int by = blockIdx.y;
  const int wsel = by >> 3;
  const int n0 = (by & 7) * 128;
  const int m0 = blockIdx.x * 128;
  const u16* Bm = (wsel == 0) ? W0 : (wsel == 1) ? W1 : W2;
  const int t = threadIdx.x;
  const int w = t >> 6;
  const int lane = t & 63;
  const int wm = w >> 1, wn = w & 1;
  const int c = lane & 15, g = lane >> 4;
  const int srow = t >> 2, skoff = (t & 3) * 8;

  f32x4 acc[4][4] = {};

  const u16* ag = A + (size_t)(m0 + srow) * Dc + skoff;
  const u16* bg = Bm + (size_t)(n0 + srow) * Dc + skoff;
  u16* al = &As[(w * 16) * 32];
  u16* bl = &Bs[(w * 16) * 32];

  for (int k0 = 0; k0 < Dc; k0 += 32) {
    gload_lds16(ag + k0, al);
    gload_lds16(ag + k0 + (size_t)64 * Dc, al + 64 * 32);
    gload_lds16(bg + k0, bl);
    gload_lds16(bg + k0 + (size_t)64 * Dc, bl + 64 * 32);
    __syncthreads();
    bf16x8 a[4], b[4];
#pragma unroll
    for (int f = 0; f < 4; ++f) {
      a[f] = *(const bf16x8*)&As[(wm * 64 + f * 16 + c) * 32 + g * 8];
      b[f] = *(const bf16x8*)&Bs[(wn * 64 + f * 16 + c) * 32 + g * 8];
    }
#pragma unroll
    for (int fm = 0; fm < 4; ++fm)
#pragma unroll
      for (int fn = 0; fn < 4; ++fn)
        acc[fm][fn] =
            __builtin_amdgcn_mfma_f32_16x16x32_bf16(a[fm], b[fn], acc[fm][fn], 0, 0, 0);
    __syncthreads();
  }

  u16* dst = (wsel == 0) ? Qo : (wsel == 1) ? Ko : Vo;
#pragma unroll
  for (int fm = 0; fm < 4; ++fm)
#pragma unroll
    for (int fn = 0; fn < 4; ++fn)
#pragma unroll
      for (int r = 0; r < 4; ++r) {
        const int m = m0 + wm * 64 + fm * 16 + g * 4 + r;
        const int n = n0 + wn * 64 + fn * 16 + c;
        const float v = acc[fm][fn][r];
        const int b = m >> 11, s = m & (Sc - 1);
        const int hh = n >> 6, d = n & 63;
        size_t idx;
        if (wsel < 2)
          idx = (((size_t)(b * Hc + hh) * Sc) + s) * HDc + d;
        else
          idx = ((size_t)(b * Hc + hh) * HDc + d) * Sc + s;
        dst[idx] = f2bf(v);
      }
}

// ---------------- final GEMM: out = ab @ wo^T, 64x128 tile, grid (64,8) ---
__global__ void gemm_out(const u16* __restrict__ A, const u16* __restrict__ Bm,
                         float* __restrict__ C) {
  __shared__ u16 As[64 * 32];
  __shared__ u16 Bs[128 * 32];
  const int m0 = blockIdx.x * 64;
  const int n0 = blockIdx.y * 128;
  const int t = threadIdx.x;
  const int w = t >> 6;
  const int lane = t & 63;
  const int wm = w >> 1, wn = w & 1;  // wave tile 32x64
  const int c = lane & 15, g = lane >> 4;
  const int srow = t >> 2, skoff = (t & 3) * 8;

  f32x4 acc[2][4] = {};

  const u16* ag = A + (size_t)(m0 + srow) * Dc + skoff;
  const u16* bg = Bm + (size_t)(n0 + srow) * Dc + skoff;
  u16* al = &As[(w * 16) * 32];
  u16* bl = &Bs[(w * 16) * 32];

  for (int k0 = 0; k0 < Dc; k0 += 32) {
    gload_lds16(ag + k0, al);
    gload_lds16(bg + k0, bl);
    gload_lds16(bg + k0 + (size_t)64 * Dc, bl + 64 * 32);
    __syncthreads();
    bf16x8 a[2], b[4];
#pragma unroll
    for (int f = 0; f < 2; ++f)
      a[f] = *(const bf16x8*)&As[(wm * 32 + f * 16 + c) * 32 + g * 8];
#pragma unroll
    for (int f = 0; f < 4; ++f)
      b[f] = *(const bf16x8*)&Bs[(wn * 64 + f * 16 + c) * 32 + g * 8];
#pragma unroll
    for (int fm = 0; fm < 2; ++fm)
#pragma unroll
      for (int fn = 0; fn < 4; ++fn)
        acc[fm][fn] =
            __builtin_amdgcn_mfma_f32_16x16x32_bf16(a[fm], b[fn], acc[fm][fn], 0, 0, 0);
    __syncthreads();
  }

#pragma unroll
  for (int fm = 0; fm < 2; ++fm)
#pragma unroll
    for (int fn = 0; fn < 4; ++fn)
#pragma unroll
      for (int r = 0; r < 4; ++r) {
        const int m = m0 + wm * 32 + fm * 16 + g * 4 + r;
        const int n = n0 + wn * 64 + fn * 16 + c;
        C[(size_t)m * Dc + n] = acc[fm][fn][r];
      }
}

// ---------------- RoPE on q (scale = HD^-0.5 * log2(e) folded) and k ------
__global__ void rope_all(u16* __restrict__ qb, u16* __restrict__ kb,
                         const float* __restrict__ freqs) {
  int idx = blockIdx.x * 256 + threadIdx.x;
  const int half = Bc * Hc * Sc * ROTc;  // 2097152 pairs per tensor
  u16* buf = qb;
  float scale = 0.125f * 1.44269504f;  // HD^-0.5 * log2e  (exp2 softmax domain)
  int p = idx;
  if (idx >= half) {
    buf = kb;
    scale = 1.0f;
    p = idx - half;
  }
  const int i = p & 31;
  const int s = (p >> 5) & (Sc - 1);
  const int bh = p >> 16;
  const float cs = freqs[(s * ROTc + i) * 2];
  const float sn = freqs[(s * ROTc + i) * 2 + 1];
  u16* ptr = buf + ((size_t)bh * Sc + s) * HDc + i * 2;
  unsigned pr = *reinterpret_cast<unsigned*>(ptr);
  float x0 = bf2f((u16)(pr & 0xffffu));
  float x1 = bf2f((u16)(pr >> 16));
  float y0 = (x0 * cs - x1 * sn) * scale;
  float y1 = (x1 * cs + x0 * sn) * scale;
  *reinterpret_cast<unsigned*>(ptr) = (unsigned)f2bf(y0) | ((unsigned)f2bf(y1) << 16);
}

// ---------------- flash attention, swapped-operand 32x32, split-KV x2 ----
// Q(BH,S,64) K(BH,S,64) Vt(BH,64,S).  4 waves x 32 q-rows = 128 q/block.
// Grid 1024 = 32 bh x 16 q-tiles x 2 kv-halves -> 4 blocks/CU (16 waves/CU).
// Each block computes online softmax over its 1024-kv half and writes a
// NORMALIZED partial O (bf16) + per-row (m, l); combine() merges halves.
// Inner loop byte-identical to the round-6-verified kernel.
__global__ __launch_bounds__(256, 4) void flash_attn(
    const u16* __restrict__ Q, const u16* __restrict__ Kb,
    const u16* __restrict__ Vt, u16* __restrict__ O0, u16* __restrict__ O1,
    float* __restrict__ pm, float* __restrict__ pl) {
  __shared__ u16 Ks[2][32 * 128];
  __shared__ u16 Vs[2][32 * 128];
  const int orig = blockIdx.x;
  const int wg = (orig & 7) * 128 + (orig >> 3);  // bijective XCD chunking
  const int bh = wg >> 5;
  const int rem = wg & 31;
  const int q0 = (rem >> 1) << 7;
  const int half = rem & 1;
  const int kvb = half << 10;  // kv range [kvb, kvb+1024)
  const int t = threadIdx.x, w = t >> 6, lane = t & 63;
  const int l31 = lane & 31, hi = lane >> 5;
  const int sr = t >> 4;
  const int su = (t & 15) ^ (sr & 15);
  const int skv = sr + ((su >> 3) << 5);  // source kv (K) / d (V) row
  const int sd8 = (su & 7) * 8;           // source col offset (u16)
  const int rsw = (l31 & 15);             // read-side slot swizzle

  const u16* Qp = Q + (size_t)bh * Sc * HDc;
  const u16* Kp = Kb + (size_t)bh * Sc * HDc;
  const u16* Vp = Vt + (size_t)bh * HDc * Sc;

  const int q = q0 + w * 32 + l31;
  bf16x8 aq[4];
#pragma unroll
  for (int kd = 0; kd < 4; ++kd)
    aq[kd] = *(const bf16x8*)(Qp + (size_t)q * HDc + kd * 16 + hi * 8);

  float m_run = -1e30f, l_run = 0.f;
  f32x16 o[2] = {};

  // prologue: stage first tile of this half into buf 0
  gload_lds16(Kp + (size_t)(kvb + skv) * HDc + sd8, &Ks[0][w * 512]);
  gload_lds16(Kp + (size_t)(kvb + skv + 16) * HDc + sd8, &Ks[0][2048 + w * 512]);
  gload_lds16(Vp + (size_t)skv * Sc + kvb + sd8, &Vs[0][w * 512]);
  gload_lds16(Vp + (size_t)(skv + 16) * Sc + kvb + sd8, &Vs[0][2048 + w * 512]);
  __syncthreads();

  int buf = 0;
  for (int t0 = kvb; t0 < kvb + 1024; t0 += 64) {
    if (t0 + 64 < kvb + 1024) {
      const int tn = t0 + 64;
      gload_lds16(Kp + (size_t)(tn + skv) * HDc + sd8, &Ks[buf ^ 1][w * 512]);
      gload_lds16(Kp + (size_t)(tn + skv + 16) * HDc + sd8, &Ks[buf ^ 1][2048 + w * 512]);
      gload_lds16(Vp + (size_t)skv * Sc + tn + sd8, &Vs[buf ^ 1][w * 512]);
      gload_lds16(Vp + (size_t)(skv + 16) * Sc + tn + sd8, &Vs[buf ^ 1][2048 + w * 512]);
    }
    // QK^T (swapped): s0 rows = kv l31 ; s1 rows = kv 32+l31 ; cols = q
    f32x16 s0 = {}, s1 = {};
    __builtin_amdgcn_s_setprio(1);
#pragma unroll
    for (int kd = 0; kd < 4; ++kd) {
      const int u0 = kd * 2 + hi;
      bf16x8 a0 = *(const bf16x8*)&Ks[buf][l31 * 128 + (u0 ^ rsw) * 8];
      bf16x8 a1 = *(const bf16x8*)&Ks[buf][l31 * 128 + ((u0 + 8) ^ rsw) * 8];
      s0 = __builtin_amdgcn_mfma_f32_32x32x16_bf16(a0, aq[kd], s0, 0, 0, 0);
      s1 = __builtin_amdgcn_mfma_f32_32x32x16_bf16(a1, aq[kd], s1, 0, 0, 0);
    }
    __builtin_amdgcn_s_setprio(0);
    // packed-f32 row max (lane-local 32 values + one cross-half shuffle)
    f32x2 t4[4];
#pragma unroll
    for (int i = 0; i < 4; ++i) {
      f32x2 e0; e0.x = s0[2 * i]; e0.y = s0[2 * i + 1];
      f32x2 e1; e1.x = s0[2 * i + 8]; e1.y = s0[2 * i + 9];
      f32x2 e2; e2.x = s1[2 * i]; e2.y = s1[2 * i + 1];
      f32x2 e3; e3.x = s1[2 * i + 8]; e3.y = s1[2 * i + 9];
      t4[i] = pmax2(pmax2(e0, e1), pmax2(e2, e3));
    }
    f32x2 tp = pmax2(pmax2(t4[0], t4[1]), pmax2(t4[2], t4[3]));
    float mt = fmaxf(tp.x, tp.y);
    mt = fmaxf(mt, __shfl_xor(mt, 32));
    // defer-max: skip rescale while tile max stays within 2^8 of running max
    const bool skip = __all(mt <= m_run + 8.0f);
    if (!skip) {
      const float mn2 = fmaxf(m_run, mt);
      const float scl = __builtin_amdgcn_exp2f(m_run - mn2);
      m_run = mn2;
      l_run *= scl;
      o[0] *= scl;
      o[1] *= scl;
    }
    const float mn = m_run;
#pragma unroll
    for (int r = 0; r < 16; ++r) {
      s0[r] = __builtin_amdgcn_exp2f(s0[r] - mn);
      s1[r] = __builtin_amdgcn_exp2f(s1[r] - mn);
    }
    // packed row sum + cross-half shuffle
    f32x2 ac;
    ac.x = 0.f; ac.y = 0.f;
#pragma unroll
    for (int i = 0; i < 8; ++i) {
      f32x2 e0; e0.x = s0[2 * i]; e0.y = s0[2 * i + 1];
      f32x2 e1; e1.x = s1[2 * i]; e1.y = s1[2 * i + 1];
      ac += e0 + e1;
    }
    float rs = ac.x + ac.y;
    rs += __shfl_xor(rs, 32);
    l_run += rs;
    // pack P to bf16 pairs: pk[kb][2B+s] covers kv = kb*32+8B+4*hi+2s(+1)
    unsigned pk0[8], pk1[8];
#pragma unroll
    for (int B = 0; B < 4; ++B)
#pragma unroll
      for (int s2 = 0; s2 < 2; ++s2) {
        pk0[B * 2 + s2] = cvtpk(s0[4 * B + 2 * s2], s0[4 * B + 2 * s2 + 1]);
        pk1[B * 2 + s2] = cvtpk(s1[4 * B + 2 * s2], s1[4 * B + 2 * s2 + 1]);
      }
    // PV: O = mfma(A=V^T, B=P); B-frag kv = ks*16 + hi*8 + j (round-4 proven)
#pragma unroll
    for (int ks = 0; ks < 4; ++ks) {
      const unsigned* pk = (ks >> 1) ? pk1 : pk0;
      const int m2 = (ks & 1) * 4;
      const unsigned A0 = pk[m2 + 0], A1 = pk[m2 + 1];
      const unsigned B0 = pk[m2 + 2], B1 = pk[m2 + 3];
      const unsigned L0 = hi ? B0 : A0, L1 = hi ? B1 : A1;  // local regs
      const unsigned R0 = hi ? A0 : B0, R1 = hi ? A1 : B1;  // export regs
      const unsigned X0 = __shfl_xor(R0, 32), X1 = __shfl_xor(R1, 32);
      union { unsigned u[4]; bf16x8 v; } bp;
      bp.u[0] = hi ? X0 : L0;
      bp.u[1] = hi ? X1 : L1;
      bp.u[2] = hi ? L0 : X0;
      bp.u[3] = hi ? L1 : X1;
      const int uv = ks * 2 + hi;
      bf16x8 va0 = *(const bf16x8*)&Vs[buf][l31 * 128 + (uv ^ rsw) * 8];
      bf16x8 va1 = *(const bf16x8*)&Vs[buf][l31 * 128 + ((uv + 8) ^ rsw) * 8];
      __builtin_amdgcn_s_setprio(1);
      o[0] = __builtin_amdgcn_mfma_f32_32x32x16_bf16(va0, bp.v, o[0], 0, 0, 0);
      o[1] = __builtin_amdgcn_mfma_f32_32x32x16_bf16(va1, bp.v, o[1], 0, 0, 0);
      __builtin_amdgcn_s_setprio(0);
    }
    __syncthreads();  // stage t+1 landed; all reads of buf done
    buf ^= 1;
  }

  // epilogue: normalized partial O -> O0 (half 0) or O1 (half 1); (m,l) -> pm/pl
  const float rl = 1.0f / l_run;
  const int b = bh >> 4, hh = bh & 15;
  u16* obase = half ? O1 : O0;
  u16* orow = obase + ((size_t)b * Sc + q) * Dc + hh * HDc;
#pragma unroll
  for (int fv = 0; fv < 2; ++fv)
#pragma unroll
    for (int B2 = 0; B2 < 4; ++B2) {
      const float v0 = o[fv][4 * B2 + 0] * rl, v1 = o[fv][4 * B2 + 1] * rl;
      const float v2 = o[fv][4 * B2 + 2] * rl, v3 = o[fv][4 * B2 + 3] * rl;
      uint2 pv;
      pv.x = cvtpk(v0, v1);
      pv.y = cvtpk(v2, v3);
      *reinterpret_cast<uint2*>(orow + fv * 32 + 8 * B2 + 4 * hi) = pv;
    }
  if (hi == 0) {
    const int row = (bh << 11) + q;
    pm[(half << 16) + row] = m_run;
    pl[(half << 16) + row] = l_run;
  }
}

// ---------------- merge the two kv-half partials: ab = merge(ab, O1) ------
__global__ void combine(const u16* __restrict__ O1, u16* __restrict__ ab,
                        const float* __restrict__ pm, const float* __restrict__ pl) {
  const int gid = blockIdx.x * 256 + threadIdx.x;  // 524288 = 65536 rows x 8
  const int row = gid >> 3, oct = gid & 3 * 2 + (gid & 7);  // (unused calc guard)
  const int oc = gid & 7;
  const int bh = row >> 11, q = row & (Sc - 1);
  const int b = bh >> 4, hh = bh & 15;
  const float m1 = pm[row], l1 = pl[row];
  const float m2 = pm[65536 + row], l2 = pl[65536 + row];
  const float mx = fmaxf(m1, m2);
  const float w1 = l1 * __builtin_amdgcn_exp2f(m1 - mx);
  const float w2 = l2 * __builtin_amdgcn_exp2f(m2 - mx);
  const float rw = 1.0f / (w1 + w2);
  const float c1 = w1 * rw, c2 = w2 * rw;
  const size_t base = ((size_t)b * Sc + q) * Dc + hh * HDc + oc * 8;
  bf16x8 x = *reinterpret_cast<const bf16x8*>(ab + base);
  bf16x8 y = *reinterpret_cast<const bf16x8*>(O1 + base);
  uint2 outv;
  float r0 = bf2f((u16)x[0]) * c1 + bf2f((u16)y[0]) * c2;
  float r1 = bf2f((u16)x[1]) * c1 + bf2f((u16)y[1]) * c2;
  float r2 = bf2f((u16)x[2]) * c1 + bf2f((u16)y[2]) * c2;
  float r3 = bf2f((u16)x[3]) * c1 + bf2f((u16)y[3]) * c2;
  float r4 = bf2f((u16)x[4]) * c1 + bf2f((u16)y[4]) * c2;
  float r5 = bf2f((u16)x[5]) * c1 + bf2f((u16)y[5]) * c2;
  float r6 = bf2f((u16)x[6]) * c1 + bf2f((u16)y[6]) * c2;
  float r7 = bf2f((u16)x[7]) * c1 + bf2f((u16)y[7]) * c2;
  outv.x = cvtpk(r0, r1);
  outv.y = cvtpk(r2, r3);
  uint2 outw;
  outw.x = cvtpk(r4, r5);
  outw.y = cvtpk(r6, r7);
  uint4 full;
  full.x = outv.x; full.y = outv.y; full.z = outw.x; full.w = outw.y;
  *reinterpret_cast<uint4*>(ab + base) = full;
  (void)oct;
}

extern "C" void kernel_launch(void* const* d_in, const int* in_sizes, int n_in,
                              void* d_out, int out_size, void* d_ws, size_t ws_size,
                              hipStream_t stream) {
  (void)in_sizes; (void)n_in; (void)out_size; (void)ws_size;
  const float* hidden = (const float*)d_in[0];
  const float* freqs = (const float*)d_in[1];
  const float* wq = (const float*)d_in[2];
  const float* wk = (const float*)d_in[3];
  const float* wv = (const float*)d_in[4];
  const float* wo = (const float*)d_in[5];
  float* out = (float*)d_out;

  char* ws = (char*)d_ws;
  const size_t MB8 = (size_t)Mrows * Dc * 2;  // 8 MiB
  const size_t WB = (size_t)Dc * Dc * 2;      // 2 MiB
  u16* hb = (u16*)ws;  ws += MB8;
  u16* wqb = (u16*)ws; ws += WB;
  u16* wkb = (u16*)ws; ws += WB;
  u16* wvb = (u16*)ws; ws += WB;
  u16* wob = (u16*)ws; ws += WB;
  u16* qb = (u16*)ws;  ws += MB8;
  u16* kb = (u16*)ws;  ws += MB8;
  u16* vtb = (u16*)ws; ws += MB8;
  u16* ab = (u16*)ws;  ws += MB8;

  // dead-after-gemm_qkv regions reused by flash partials:
  u16* po = hb;              // half-1 partial O (8 MiB, exact fit)
  float* pm = (float*)wqb;   // [2][65536] tile maxes (512 KiB)
  float* pl = pm + 2 * 65536;  // [2][65536] sums (512 KiB) — within wqb+wkb

  cvt_all<<<8192, 256, 0, stream>>>(hidden, wq, wk, wv, wo, hb, wqb, wkb, wvb, wob);
  gemm_qkv<<<dim3(32, 24), 256, 0, stream>>>(hb, wqb, wkb, wvb, qb, kb, vtb);
  rope_all<<<16384, 256, 0, stream>>>(qb, kb, freqs);
  flash_attn<<<1024, 256, 0, stream>>>(qb, kb, vtb, ab, po, pm, pl);
  combine<<<2048, 256, 0, stream>>>(po, ab, pm, pl);
  gemm_out<<<dim3(64, 8), 256, 0, stream>>>(ab, wob, out);
}

// Round 9
// 137.938 us; speedup vs baseline: 1.1196x; 1.1196x over previous
//
#include <hip/hip_runtime.h>
#include <hip/hip_bf16.h>

typedef __attribute__((ext_vector_type(8))) short bf16x8;
typedef __attribute__((ext_vector_type(4))) float f32x4;
typedef __attribute__((ext_vector_type(16))) float f32x16;
typedef __attribute__((ext_vector_type(2))) float f32x2;
typedef unsigned short u16;

#define Bc   2
#define Sc   2048
#define Dc   1024
#define Hc   16
#define HDc  64
#define ROTc 32
#define Mrows 4096  // B*S

__device__ __forceinline__ u16 f2bf(float x) {
  union { float f; unsigned u; } v{x};
  unsigned r = v.u + 0x7fffu + ((v.u >> 16) & 1u);
  return (u16)(r >> 16);
}
__device__ __forceinline__ float bf2f(u16 x) {
  union { unsigned u; float f; } v{(unsigned)x << 16};
  return v.f;
}
__device__ __forceinline__ unsigned cvtpk(float a, float b) {
  unsigned r;
  asm("v_cvt_pk_bf16_f32 %0, %1, %2" : "=v"(r) : "v"(a), "v"(b));
  return r;
}
__device__ __forceinline__ f32x2 pmax2(f32x2 a, f32x2 b) {
  f32x2 r;
  r.x = fmaxf(a.x, b.x);
  r.y = fmaxf(a.y, b.y);
  return r;
}

__device__ __forceinline__ void gload_lds16(const void* g, void* l) {
  __builtin_amdgcn_global_load_lds(
      (const __attribute__((address_space(1))) void*)g,
      (__attribute__((address_space(3))) void*)l, 16, 0, 0);
}

// ---------------- f32 -> bf16 conversion (hidden + 4 weights in one grid) --
__global__ void cvt_all(const float* __restrict__ h, const float* __restrict__ q,
                        const float* __restrict__ k, const float* __restrict__ v,
                        const float* __restrict__ o,
                        u16* __restrict__ hb, u16* __restrict__ qb, u16* __restrict__ kb,
                        u16* __restrict__ vb, u16* __restrict__ ob) {
  size_t i = ((size_t)blockIdx.x * 256 + threadIdx.x) * 4;
  const float* s;
  u16* d;
  size_t off;
  if (i < (size_t)Mrows * Dc) {
    s = h; d = hb; off = i;
  } else {
    size_t j = i - (size_t)Mrows * Dc;
    int w = (int)(j >> 20);            // 1M elements per weight
    off = j & ((1u << 20) - 1);
    s = (w == 0) ? q : (w == 1) ? k : (w == 2) ? v : o;
    d = (w == 0) ? qb : (w == 1) ? kb : (w == 2) ? vb : ob;
  }
  float4 val = *reinterpret_cast<const float4*>(s + off);
  u16 r0 = f2bf(val.x), r1 = f2bf(val.y), r2 = f2bf(val.z), r3 = f2bf(val.w);
  ushort4 outv = {r0, r1, r2, r3};
  *reinterpret_cast<ushort4*>(d + off) = outv;
}

// ---------------- fused QKV NT GEMM + RoPE epilogue, grid (32, 24) --------
// blockIdx.y: [0,8)=Q(+rope+scale), [8,16)=K(+rope), [16,24)=V(transposed).
// RoPE in-epilogue: pair (d=2i,2i+1) lives in lanes c, c^1 of the same
// fragment -> one shfl_xor(1) + fma with freqs[s][i] (f32, pre-rounding).
__global__ void gemm_qkv(const u16* __restrict__ A, const u16* __restrict__ W0,
                         const u16* __restrict__ W1, const u16* __restrict__ W2,
                         const float* __restrict__ freqs,
                         u16* __restrict__ Qo, u16* __restrict__ Ko,
                         u16* __restrict__ Vo) {
  __shared__ u16 As[128 * 32];
  __shared__ u16 Bs[128 * 32];
  const int by = blockIdx.y;
  const int wsel = by >> 3;
  const int n0 = (by & 7) * 128;
  const int m0 = blockIdx.x * 128;
  const u16* Bm = (wsel == 0) ? W0 : (wsel == 1) ? W1 : W2;
  const int t = threadIdx.x;
  const int w = t >> 6;
  const int lane = t & 63;
  const int wm = w >> 1, wn = w & 1;
  const int c = lane & 15, g = lane >> 4;
  const int srow = t >> 2, skoff = (t & 3) * 8;

  f32x4 acc[4][4] = {};

  const u16* ag = A + (size_t)(m0 + srow) * Dc + skoff;
  const u16* bg = Bm + (size_t)(n0 + srow) * Dc + skoff;
  u16* al = &As[(w * 16) * 32];
  u16* bl = &Bs[(w * 16) * 32];

  for (int k0 = 0; k0 < Dc; k0 += 32) {
    gload_lds16(ag + k0, al);
    gload_lds16(ag + k0 + (size_t)64 * Dc, al + 64 * 32);
    gload_lds16(bg + k0, bl);
    gload_lds16(bg + k0 + (size_t)64 * Dc, bl + 64 * 32);
    __syncthreads();
    bf16x8 a[4], b[4];
#pragma unroll
    for (int f = 0; f < 4; ++f) {
      a[f] = *(const bf16x8*)&As[(wm * 64 + f * 16 + c) * 32 + g * 8];
      b[f] = *(const bf16x8*)&Bs[(wn * 64 + f * 16 + c) * 32 + g * 8];
    }
#pragma unroll
    for (int fm = 0; fm < 4; ++fm)
#pragma unroll
      for (int fn = 0; fn < 4; ++fn)
        acc[fm][fn] =
            __builtin_amdgcn_mfma_f32_16x16x32_bf16(a[fm], b[fn], acc[fm][fn], 0, 0, 0);
    __syncthreads();
  }

  u16* dst = (wsel == 0) ? Qo : (wsel == 1) ? Ko : Vo;
  const float qsc = (wsel == 0) ? 0.125f * 1.44269504f : 1.0f;  // HD^-0.5*log2e
  const int codd = c & 1;
#pragma unroll
  for (int fm = 0; fm < 4; ++fm)
#pragma unroll
    for (int fn = 0; fn < 4; ++fn)
#pragma unroll
      for (int r = 0; r < 4; ++r) {
        const int m = m0 + wm * 64 + fm * 16 + g * 4 + r;
        const int n = n0 + wn * 64 + fn * 16 + c;
        float v = acc[fm][fn][r];
        const int b = m >> 11, s = m & (Sc - 1);
        const int hh = n >> 6, d = n & 63;
        size_t idx;
        if (wsel < 2) {
          // RoPE: partner value sits in lane^1 (same fragment indices)
          const float other = __shfl_xor(v, 1);
          const float2 f = reinterpret_cast<const float2*>(freqs)[s * ROTc + (d >> 1)];
          v = codd ? (v * f.x + other * f.y) : (v * f.x - other * f.y);
          v *= qsc;
          idx = (((size_t)(b * Hc + hh) * Sc) + s) * HDc + d;
        } else {
          idx = ((size_t)(b * Hc + hh) * HDc + d) * Sc + s;
        }
        dst[idx] = f2bf(v);
      }
}

// ---------------- final GEMM: out = ab @ wo^T, 64x128 tile, grid (64,8) ---
__global__ void gemm_out(const u16* __restrict__ A, const u16* __restrict__ Bm,
                         float* __restrict__ C) {
  __shared__ u16 As[64 * 32];
  __shared__ u16 Bs[128 * 32];
  const int m0 = blockIdx.x * 64;
  const int n0 = blockIdx.y * 128;
  const int t = threadIdx.x;
  const int w = t >> 6;
  const int lane = t & 63;
  const int wm = w >> 1, wn = w & 1;  // wave tile 32x64
  const int c = lane & 15, g = lane >> 4;
  const int srow = t >> 2, skoff = (t & 3) * 8;

  f32x4 acc[2][4] = {};

  const u16* ag = A + (size_t)(m0 + srow) * Dc + skoff;
  const u16* bg = Bm + (size_t)(n0 + srow) * Dc + skoff;
  u16* al = &As[(w * 16) * 32];
  u16* bl = &Bs[(w * 16) * 32];

  for (int k0 = 0; k0 < Dc; k0 += 32) {
    gload_lds16(ag + k0, al);
    gload_lds16(bg + k0, bl);
    gload_lds16(bg + k0 + (size_t)64 * Dc, bl + 64 * 32);
    __syncthreads();
    bf16x8 a[2], b[4];
#pragma unroll
    for (int f = 0; f < 2; ++f)
      a[f] = *(const bf16x8*)&As[(wm * 32 + f * 16 + c) * 32 + g * 8];
#pragma unroll
    for (int f = 0; f < 4; ++f)
      b[f] = *(const bf16x8*)&Bs[(wn * 64 + f * 16 + c) * 32 + g * 8];
#pragma unroll
    for (int fm = 0; fm < 2; ++fm)
#pragma unroll
      for (int fn = 0; fn < 4; ++fn)
        acc[fm][fn] =
            __builtin_amdgcn_mfma_f32_16x16x32_bf16(a[fm], b[fn], acc[fm][fn], 0, 0, 0);
    __syncthreads();
  }

#pragma unroll
  for (int fm = 0; fm < 2; ++fm)
#pragma unroll
    for (int fn = 0; fn < 4; ++fn)
#pragma unroll
      for (int r = 0; r < 4; ++r) {
        const int m = m0 + wm * 32 + fm * 16 + g * 4 + r;
        const int n = n0 + wn * 64 + fn * 16 + c;
        C[(size_t)m * Dc + n] = acc[fm][fn][r];
      }
}

// ---------------- flash attention, swapped-operand 32x32 (round-7 proven) -
// Q(BH,S,64) K(BH,S,64) Vt(BH,64,S).  4 waves x 32 q-rows = 128 q/block.
// 1D grid 512, bijective XCD chunking. LDS fused-row layout: phys row r
// (0..31, 256B) holds src rows {r, r+32}; 16 slots of 16B, slot = u^(r&15).
// exp2 via raw v_exp_f32; cross-half exchange via __shfl_xor.
// NOTE: split-KV x2 tried (round 8): occupancy 18->34% but 3x WRITE_SIZE
// + combine pass => net -16 us. Do not reintroduce.
__global__ __launch_bounds__(256, 2) void flash_attn(
    const u16* __restrict__ Q, const u16* __restrict__ Kb,
    const u16* __restrict__ Vt, u16* __restrict__ Ob) {
  __shared__ u16 Ks[2][32 * 128];
  __shared__ u16 Vs[2][32 * 128];
  const int orig = blockIdx.x;
  const int wg = (orig & 7) * 64 + (orig >> 3);  // bijective XCD chunking
  const int bh = wg >> 4;
  const int q0 = (wg & 15) * 128;
  const int t = threadIdx.x, w = t >> 6, lane = t & 63;
  const int l31 = lane & 31, hi = lane >> 5;
  const int sr = t >> 4;
  const int su = (t & 15) ^ (sr & 15);
  const int skv = sr + ((su >> 3) << 5);  // source kv (K) / d (V) row
  const int sd8 = (su & 7) * 8;           // source col offset (u16)
  const int rsw = (l31 & 15);             // read-side slot swizzle

  const u16* Qp = Q + (size_t)bh * Sc * HDc;
  const u16* Kp = Kb + (size_t)bh * Sc * HDc;
  const u16* Vp = Vt + (size_t)bh * HDc * Sc;

  const int q = q0 + w * 32 + l31;
  bf16x8 aq[4];
#pragma unroll
  for (int kd = 0; kd < 4; ++kd)
    aq[kd] = *(const bf16x8*)(Qp + (size_t)q * HDc + kd * 16 + hi * 8);

  float m_run = -1e30f, l_run = 0.f;
  f32x16 o[2] = {};

  // prologue: stage tile 0 into buf 0 (2 x 256thr x 16B per tensor)
  gload_lds16(Kp + (size_t)skv * HDc + sd8, &Ks[0][w * 512]);
  gload_lds16(Kp + (size_t)(skv + 16) * HDc + sd8, &Ks[0][2048 + w * 512]);
  gload_lds16(Vp + (size_t)skv * Sc + sd8, &Vs[0][w * 512]);
  gload_lds16(Vp + (size_t)(skv + 16) * Sc + sd8, &Vs[0][2048 + w * 512]);
  __syncthreads();

  int buf = 0;
  for (int t0 = 0; t0 < Sc; t0 += 64) {
    if (t0 + 64 < Sc) {
      const int tn = t0 + 64;
      gload_lds16(Kp + (size_t)(tn + skv) * HDc + sd8, &Ks[buf ^ 1][w * 512]);
      gload_lds16(Kp + (size_t)(tn + skv + 16) * HDc + sd8, &Ks[buf ^ 1][2048 + w * 512]);
      gload_lds16(Vp + (size_t)skv * Sc + tn + sd8, &Vs[buf ^ 1][w * 512]);
      gload_lds16(Vp + (size_t)(skv + 16) * Sc + tn + sd8, &Vs[buf ^ 1][2048 + w * 512]);
    }
    // QK^T (swapped): s0 rows = kv l31 ; s1 rows = kv 32+l31 ; cols = q
    f32x16 s0 = {}, s1 = {};
    __builtin_amdgcn_s_setprio(1);
#pragma unroll
    for (int kd = 0; kd < 4; ++kd) {
      const int u0 = kd * 2 + hi;
      bf16x8 a0 = *(const bf16x8*)&Ks[buf][l31 * 128 + (u0 ^ rsw) * 8];
      bf16x8 a1 = *(const bf16x8*)&Ks[buf][l31 * 128 + ((u0 + 8) ^ rsw) * 8];
      s0 = __builtin_amdgcn_mfma_f32_32x32x16_bf16(a0, aq[kd], s0, 0, 0, 0);
      s1 = __builtin_amdgcn_mfma_f32_32x32x16_bf16(a1, aq[kd], s1, 0, 0, 0);
    }
    __builtin_amdgcn_s_setprio(0);
    // packed-f32 row max (lane-local 32 values + one cross-half shuffle)
    f32x2 t4[4];
#pragma unroll
    for (int i = 0; i < 4; ++i) {
      f32x2 e0; e0.x = s0[2 * i]; e0.y = s0[2 * i + 1];
      f32x2 e1; e1.x = s0[2 * i + 8]; e1.y = s0[2 * i + 9];
      f32x2 e2; e2.x = s1[2 * i]; e2.y = s1[2 * i + 1];
      f32x2 e3; e3.x = s1[2 * i + 8]; e3.y = s1[2 * i + 9];
      t4[i] = pmax2(pmax2(e0, e1), pmax2(e2, e3));
    }
    f32x2 tp = pmax2(pmax2(t4[0], t4[1]), pmax2(t4[2], t4[3]));
    float mt = fmaxf(tp.x, tp.y);
    mt = fmaxf(mt, __shfl_xor(mt, 32));
    // defer-max: skip rescale while tile max stays within 2^8 of running max
    const bool skip = __all(mt <= m_run + 8.0f);
    if (!skip) {
      const float mn2 = fmaxf(m_run, mt);
      const float scl = __builtin_amdgcn_exp2f(m_run - mn2);
      m_run = mn2;
      l_run *= scl;
      o[0] *= scl;
      o[1] *= scl;
    }
    const float mn = m_run;
#pragma unroll
    for (int r = 0; r < 16; ++r) {
      s0[r] = __builtin_amdgcn_exp2f(s0[r] - mn);
      s1[r] = __builtin_amdgcn_exp2f(s1[r] - mn);
    }
    // packed row sum + cross-half shuffle
    f32x2 ac;
    ac.x = 0.f; ac.y = 0.f;
#pragma unroll
    for (int i = 0; i < 8; ++i) {
      f32x2 e0; e0.x = s0[2 * i]; e0.y = s0[2 * i + 1];
      f32x2 e1; e1.x = s1[2 * i]; e1.y = s1[2 * i + 1];
      ac += e0 + e1;
    }
    float rs = ac.x + ac.y;
    rs += __shfl_xor(rs, 32);
    l_run += rs;
    // pack P to bf16 pairs: pk[kb][2B+s] covers kv = kb*32+8B+4*hi+2s(+1)
    unsigned pk0[8], pk1[8];
#pragma unroll
    for (int B = 0; B < 4; ++B)
#pragma unroll
      for (int s2 = 0; s2 < 2; ++s2) {
        pk0[B * 2 + s2] = cvtpk(s0[4 * B + 2 * s2], s0[4 * B + 2 * s2 + 1]);
        pk1[B * 2 + s2] = cvtpk(s1[4 * B + 2 * s2], s1[4 * B + 2 * s2 + 1]);
      }
    // PV: O = mfma(A=V^T, B=P); B-frag kv = ks*16 + hi*8 + j (round-4 proven)
#pragma unroll
    for (int ks = 0; ks < 4; ++ks) {
      const unsigned* pk = (ks >> 1) ? pk1 : pk0;
      const int m2 = (ks & 1) * 4;
      const unsigned A0 = pk[m2 + 0], A1 = pk[m2 + 1];
      const unsigned B0 = pk[m2 + 2], B1 = pk[m2 + 3];
      const unsigned L0 = hi ? B0 : A0, L1 = hi ? B1 : A1;  // local regs
      const unsigned R0 = hi ? A0 : B0, R1 = hi ? A1 : B1;  // export regs
      const unsigned X0 = __shfl_xor(R0, 32), X1 = __shfl_xor(R1, 32);
      union { unsigned u[4]; bf16x8 v; } bp;
      bp.u[0] = hi ? X0 : L0;
      bp.u[1] = hi ? X1 : L1;
      bp.u[2] = hi ? L0 : X0;
      bp.u[3] = hi ? L1 : X1;
      const int uv = ks * 2 + hi;
      bf16x8 va0 = *(const bf16x8*)&Vs[buf][l31 * 128 + (uv ^ rsw) * 8];
      bf16x8 va1 = *(const bf16x8*)&Vs[buf][l31 * 128 + ((uv + 8) ^ rsw) * 8];
      __builtin_amdgcn_s_setprio(1);
      o[0] = __builtin_amdgcn_mfma_f32_32x32x16_bf16(va0, bp.v, o[0], 0, 0, 0);
      o[1] = __builtin_amdgcn_mfma_f32_32x32x16_bf16(va1, bp.v, o[1], 0, 0, 0);
      __builtin_amdgcn_s_setprio(0);
    }
    __syncthreads();  // stage t+1 landed; all reads of buf done
    buf ^= 1;
  }

  // epilogue: d = fv*32 + 8*B2 + 4*hi + rr for o[fv][4*B2+rr], row = q
  const float rl = 1.0f / l_run;
  const int b = bh >> 4, hh = bh & 15;
  u16* orow = Ob + ((size_t)b * Sc + q) * Dc + hh * HDc;
#pragma unroll
  for (int fv = 0; fv < 2; ++fv)
#pragma unroll
    for (int B2 = 0; B2 < 4; ++B2) {
      const float v0 = o[fv][4 * B2 + 0] * rl, v1 = o[fv][4 * B2 + 1] * rl;
      const float v2 = o[fv][4 * B2 + 2] * rl, v3 = o[fv][4 * B2 + 3] * rl;
      uint2 pv;
      pv.x = cvtpk(v0, v1);
      pv.y = cvtpk(v2, v3);
      *reinterpret_cast<uint2*>(orow + fv * 32 + 8 * B2 + 4 * hi) = pv;
    }
}

extern "C" void kernel_launch(void* const* d_in, const int* in_sizes, int n_in,
                              void* d_out, int out_size, void* d_ws, size_t ws_size,
                              hipStream_t stream) {
  (void)in_sizes; (void)n_in; (void)out_size; (void)ws_size;
  const float* hidden = (const float*)d_in[0];
  const float* freqs = (const float*)d_in[1];
  const float* wq = (const float*)d_in[2];
  const float* wk = (const float*)d_in[3];
  const float* wv = (const float*)d_in[4];
  const float* wo = (const float*)d_in[5];
  float* out = (float*)d_out;

  char* ws = (char*)d_ws;
  const size_t MB8 = (size_t)Mrows * Dc * 2;  // 8 MiB
  const size_t WB = (size_t)Dc * Dc * 2;      // 2 MiB
  u16* hb = (u16*)ws;  ws += MB8;
  u16* wqb = (u16*)ws; ws += WB;
  u16* wkb = (u16*)ws; ws += WB;
  u16* wvb = (u16*)ws; ws += WB;
  u16* wob = (u16*)ws; ws += WB;
  u16* qb = (u16*)ws;  ws += MB8;
  u16* kb = (u16*)ws;  ws += MB8;
  u16* vtb = (u16*)ws; ws += MB8;
  u16* ab = (u16*)ws;  ws += MB8;

  cvt_all<<<8192, 256, 0, stream>>>(hidden, wq, wk, wv, wo, hb, wqb, wkb, wvb, wob);
  gemm_qkv<<<dim3(32, 24), 256, 0, stream>>>(hb, wqb, wkb, wvb, freqs, qb, kb, vtb);
  flash_attn<<<512, 256, 0, stream>>>(qb, kb, vtb, ab);
  gemm_out<<<dim3(64, 8), 256, 0, stream>>>(ab, wob, out);
}